// Round 4
// baseline (12625.867 us; speedup 1.0000x reference)
//
#include <hip/hip_runtime.h>
#include <hip/hip_bf16.h>
#include <cstdio>

// ---------- types / helpers ----------
typedef __attribute__((ext_vector_type(4))) float f32x4;
typedef __attribute__((ext_vector_type(8))) short bf16x8;  // 8 bf16 raw

__device__ __forceinline__ short f2b(float f) {
  unsigned u = __builtin_bit_cast(unsigned, f);
  unsigned r = (u + 0x7FFFu + ((u >> 16) & 1u)) >> 16;  // RNE
  return (short)r;
}
__device__ __forceinline__ float b2f(short s) {
  union { unsigned u; float f; } c;
  c.u = ((unsigned)(unsigned short)s) << 16;
  return c.f;
}
__device__ __forceinline__ float sigm(float x) { return 1.f / (1.f + __expf(-x)); }
__device__ __forceinline__ float tanh_f(float x) {
  float e = __expf(2.f * x);
  return 1.f - 2.f / (e + 1.f);   // stable for |x| large
}

// Problem dims: B=8 T=64 F=8 N=4096 H=32 G=32 K1=K2=3 R1=64 R2=8

// ---------- fp32 -> bf16 convert (8 elements per thread) ----------
__global__ void conv_k(const float* __restrict__ in, short* __restrict__ out, int n8) {
  int i = blockIdx.x * 256 + threadIdx.x;
  if (i >= n8) return;
  size_t base = (size_t)i * 8;
  f32x4 a = *(const f32x4*)(in + base), b = *(const f32x4*)(in + base + 4);
  bf16x8 v;
#pragma unroll
  for (int j = 0; j < 4; ++j) { v[j] = f2b(a[j]); v[4 + j] = f2b(b[j]); }
  *(bf16x8*)(out + base) = v;
}

// ---------- transpose+convert (fp32 4096x4096 -> bf16): out[p][m] = in[m][p] ----------
__global__ void transpose_k(const float* __restrict__ in, short* __restrict__ out) {
  __shared__ float tile[32][33];
  int bx = blockIdx.x * 32, by = blockIdx.y * 32;
  int tx = threadIdx.x, ty = threadIdx.y;
  for (int i = ty; i < 32; i += 8)
    tile[i][tx] = in[(size_t)(by + i) * 4096 + bx + tx];
  __syncthreads();
  for (int i = ty; i < 32; i += 8)
    out[(size_t)(bx + i) * 4096 + by + tx] = f2b(tile[tx][i]);
}

// ---------- GEMM: C[M][N] = A[M][K] * Bt[N][K]^T, C bf16, fp32 accum ----------
// AF32: A is fp32 (converted to bf16 during LDS staging); else A is bf16.
// grid = (N/128, M/128), block = 256 (4 waves 2x2; each wave 64x64 = 4x4 frags of 16x16)
template <int AF32>
__global__ __launch_bounds__(256) void gemm_bt(const void* __restrict__ Av,
                                               const short* __restrict__ Bt,
                                               short* __restrict__ C,
                                               int K, int ldc) {
  __shared__ __align__(16) short As[128][72];  // +8 pad (rows 144B, 16B-aligned)
  __shared__ __align__(16) short Bs[128][72];
  const int tid = threadIdx.x;
  const int lane = tid & 63, wave = tid >> 6;
  const int wm = wave >> 1, wn = wave & 1;
  const size_t m0 = (size_t)blockIdx.y * 128, n0 = (size_t)blockIdx.x * 128;
  const int r16 = lane & 15, g4 = lane >> 4;

  f32x4 acc[4][4];
#pragma unroll
  for (int mi = 0; mi < 4; ++mi)
#pragma unroll
    for (int ni = 0; ni < 4; ++ni) acc[mi][ni] = (f32x4)0.f;

  for (int kt = 0; kt < K; kt += 64) {
#pragma unroll
    for (int r = 0; r < 4; ++r) {
      int idx = r * 256 + tid;       // 0..1023
      int row = idx >> 3;            // 0..127
      int kin = (idx & 7) * 8;       // 0..56
      if (AF32) {
        const float* A = (const float*)Av;
        const float* p = &A[(m0 + row) * (size_t)K + kt + kin];
        f32x4 a = *(const f32x4*)p, b = *(const f32x4*)(p + 4);
        bf16x8 v;
#pragma unroll
        for (int j = 0; j < 4; ++j) { v[j] = f2b(a[j]); v[4 + j] = f2b(b[j]); }
        *(bf16x8*)&As[row][kin] = v;
      } else {
        const short* A = (const short*)Av;
        *(bf16x8*)&As[row][kin] = *(const bf16x8*)&A[(m0 + row) * (size_t)K + kt + kin];
      }
      *(bf16x8*)&Bs[row][kin] = *(const bf16x8*)&Bt[(n0 + row) * (size_t)K + kt + kin];
    }
    __syncthreads();
#pragma unroll
    for (int ks = 0; ks < 2; ++ks) {
      bf16x8 af[4], bfr[4];
#pragma unroll
      for (int i = 0; i < 4; ++i) {
        af[i]  = *(const bf16x8*)&As[wm * 64 + i * 16 + r16][ks * 32 + g4 * 8];
        bfr[i] = *(const bf16x8*)&Bs[wn * 64 + i * 16 + r16][ks * 32 + g4 * 8];
      }
#pragma unroll
      for (int mi = 0; mi < 4; ++mi)
#pragma unroll
        for (int ni = 0; ni < 4; ++ni)
          acc[mi][ni] = __builtin_amdgcn_mfma_f32_16x16x32_bf16(af[mi], bfr[ni], acc[mi][ni], 0, 0, 0);
    }
    __syncthreads();
  }
  // D layout: col=lane&15, row=(lane>>4)*4+reg
#pragma unroll
  for (int mi = 0; mi < 4; ++mi) {
#pragma unroll
    for (int ni = 0; ni < 4; ++ni) {
      size_t row0 = m0 + wm * 64 + mi * 16 + g4 * 4;
      size_t col  = n0 + wn * 64 + ni * 16 + r16;
#pragma unroll
      for (int r = 0; r < 4; ++r)
        C[(row0 + r) * (size_t)ldc + col] = f2b(acc[mi][ni][r]);
    }
  }
}

// ---------- per-step gates + za/zb ----------
// grid = 512 (= b*64 + nchunk), block = 256 (64 n x 4 h-groups of 8)
// zst: fp32 z_t [b*32+h][4096]; zsht: bf16 shifts [b*32+h][8192] (tap1 | tap2)
__global__ __launch_bounds__(256) void gate_kernel(
    const float* __restrict__ x, const short* __restrict__ xsh,
    const float* __restrict__ zst, const short* __restrict__ zsht,
    const float* __restrict__ Ca, const float* __restrict__ Cb, const float* __restrict__ bc,
    const float* __restrict__ Da, const float* __restrict__ Db, const float* __restrict__ bd,
    const float* __restrict__ Af, const float* __restrict__ Bw,
    float* __restrict__ zab, float* __restrict__ gacc, int t) {
  __shared__ __align__(16) float Fu[120][32], Fd[120][32], Fb[96][32], Fa[24][32];
  __shared__ __align__(16) float bcs[32], bds[32];
  __shared__ float red[8];
  const int tid = threadIdx.x;
  for (int i = tid; i < 120 * 32; i += 256) {
    int j = i >> 5, h = i & 31;
    float fu, fd;
    if (j < 96) { int k = j >> 5, hh = j & 31;
      fu = Cb[(h * 3 + k) * 32 + hh]; fd = Db[(h * 3 + k) * 32 + hh]; }
    else { int jj = j - 96, k = jj >> 3, f = jj & 7;
      fu = Ca[(h * 3 + k) * 8 + f];  fd = Da[(h * 3 + k) * 8 + f]; }
    Fu[j][h] = fu; Fd[j][h] = fd;
  }
  for (int i = tid; i < 96 * 32; i += 256) { int j = i >> 5, h = i & 31; int k = j >> 5, hh = j & 31;
    Fb[j][h] = Bw[(h * 3 + k) * 32 + hh]; }
  for (int i = tid; i < 24 * 32; i += 256) { int j = i >> 5, h = i & 31; int k = j >> 3, f = j & 7;
    Fa[j][h] = Af[(h * 3 + k) * 8 + f]; }
  if (tid < 32) { bcs[tid] = bc[tid]; bds[tid] = bd[tid]; }
  __syncthreads();

  const int b = blockIdx.x >> 6, chunk = blockIdx.x & 63;
  const int nn = tid & 63, hg = tid >> 6, h0 = hg * 8;
  const int n = chunk * 64 + nn;
  const size_t zrow = (size_t)b * 32;

  f32x4 guA = *(const f32x4*)&bcs[h0], guB = *(const f32x4*)&bcs[h0 + 4];
  f32x4 gdA = *(const f32x4*)&bds[h0], gdB = *(const f32x4*)&bds[h0 + 4];
  f32x4 zaA = (f32x4)0.f, zaB = (f32x4)0.f, zbA = (f32x4)0.f, zbB = (f32x4)0.f;

  for (int j = 0; j < 96; ++j) {                 // z-part: j = k*32 + h'
    int k = j >> 5, hh = j & 31;
    float v = (k == 0) ? zst[(zrow + hh) * 4096 + n]
                       : b2f(zsht[(zrow + hh) * 8192 + (size_t)(k - 1) * 4096 + n]);
    f32x4 u0 = *(const f32x4*)&Fu[j][h0], u1 = *(const f32x4*)&Fu[j][h0 + 4];
    f32x4 d0 = *(const f32x4*)&Fd[j][h0], d1 = *(const f32x4*)&Fd[j][h0 + 4];
    f32x4 p0 = *(const f32x4*)&Fb[j][h0], p1 = *(const f32x4*)&Fb[j][h0 + 4];
    guA += u0 * v; guB += u1 * v; gdA += d0 * v; gdB += d1 * v; zbA += p0 * v; zbB += p1 * v;
  }
  const size_t xrow = ((size_t)b * 64 + t) * 8;  // (b*T+t)*F
  for (int j = 0; j < 24; ++j) {                 // x-part: j = k*8 + f
    int k = j >> 3, f = j & 7;
    float v = (k == 0) ? x[(xrow + f) * 4096 + n]
                       : b2f(xsh[(xrow + f) * 8192 + (size_t)(k - 1) * 4096 + n]);
    f32x4 u0 = *(const f32x4*)&Fu[96 + j][h0], u1 = *(const f32x4*)&Fu[96 + j][h0 + 4];
    f32x4 d0 = *(const f32x4*)&Fd[96 + j][h0], d1 = *(const f32x4*)&Fd[96 + j][h0 + 4];
    f32x4 a0 = *(const f32x4*)&Fa[j][h0],      a1 = *(const f32x4*)&Fa[j][h0 + 4];
    guA += u0 * v; guB += u1 * v; gdA += d0 * v; gdB += d1 * v; zaA += a0 * v; zaB += a1 * v;
  }

  float su = 0.f, sd = 0.f;
#pragma unroll
  for (int i = 0; i < 4; ++i) {
    su += sigm(guA[i]) + sigm(guB[i]);
    sd += sigm(gdA[i]) + sigm(gdB[i]);
    zab[(zrow + h0 + i) * 4096 + n]               = zaA[i];
    zab[(zrow + h0 + 4 + i) * 4096 + n]           = zaB[i];
    zab[1048576 + (zrow + h0 + i) * 4096 + n]     = zbA[i];
    zab[1048576 + (zrow + h0 + 4 + i) * 4096 + n] = zbB[i];
  }
  for (int off = 32; off; off >>= 1) { su += __shfl_down(su, off); sd += __shfl_down(sd, off); }
  const int wv = tid >> 6;
  if ((tid & 63) == 0) { red[wv] = su; red[4 + wv] = sd; }
  __syncthreads();
  if (tid == 0) {
    atomicAdd(&gacc[b],     red[0] + red[1] + red[2] + red[3]);
    atomicAdd(&gacc[8 + b], red[4] + red[5] + red[6] + red[7]);
  }
}

// ---------- per-step state update (fp32 z state) ----------
__global__ __launch_bounds__(256) void update_kernel(
    const float* __restrict__ zab, const float* __restrict__ gacc,
    const float* __restrict__ bz, float* __restrict__ zout) {
  size_t idx = (size_t)blockIdx.x * 256 + threadIdx.x;   // 131072 threads
  size_t base = idx * 8;
  int row = (int)(base >> 12);
  int b = row >> 5, h = row & 31;
  float u  = gacc[b]     * (1.f / 131072.f);
  float fg = gacc[8 + b] * (1.f / 131072.f);
  float bzv = bz[h];
  f32x4 za0 = *(const f32x4*)(zab + base),           za1 = *(const f32x4*)(zab + base + 4);
  f32x4 zb0 = *(const f32x4*)(zab + 1048576 + base), zb1 = *(const f32x4*)(zab + 1048576 + base + 4);
  f32x4 o0, o1;
#pragma unroll
  for (int i = 0; i < 4; ++i) {
    o0[i] = tanh_f(u * za0[i] + fg * zb0[i] + bzv);
    o1[i] = tanh_f(u * za1[i] + fg * zb1[i] + bzv);
  }
  *(f32x4*)(zout + base) = o0;
  *(f32x4*)(zout + base + 4) = o1;
}

// ---------- output stage for ONE time index tau: Wout filter + tanh + node MLP ----------
// grid = (16 nchunks, 8 batches), block = 256 (1 thread per n)
__global__ __launch_bounds__(256) void out_kernel(
    const float* __restrict__ zst, const short* __restrict__ zsht,
    const float* __restrict__ Wout, const float* __restrict__ bout,
    const float* __restrict__ W1, const float* __restrict__ b1,
    const float* __restrict__ W2, const float* __restrict__ b2,
    float* __restrict__ out, int tau) {
  __shared__ __align__(16) float Wc[96][32], W1L[64][32], W2L[64][8];
  __shared__ __align__(16) float boutL[32], b1L[64], b2L[8];
  const int tid = threadIdx.x;
  for (int i = tid; i < 96 * 32; i += 256) { int j = i >> 5, g = i & 31; int k = j >> 5, hh = j & 31;
    Wc[j][g] = Wout[(g * 3 + k) * 32 + hh]; }
  for (int i = tid; i < 64 * 32; i += 256) { int r1 = i >> 5, g = i & 31; W1L[r1][g] = W1[r1 * 32 + g]; }
  for (int i = tid; i < 512; i += 256) { int r1 = i >> 3, r = i & 7; W2L[r1][r] = W2[r * 64 + r1]; }
  if (tid < 32) boutL[tid] = bout[tid];
  if (tid < 64) b1L[tid] = b1[tid];
  if (tid < 8)  b2L[tid] = b2[tid];
  __syncthreads();

  const int b = blockIdx.y, chunk = blockIdx.x;
  const int n = chunk * 256 + tid;
  const size_t zbase   = (size_t)b * 32 * 4096;
  const size_t zshbase = (size_t)b * 32 * 8192;

  f32x4 acc[8];
#pragma unroll
  for (int q = 0; q < 8; ++q) acc[q] = (f32x4)0.f;
  for (int j = 0; j < 96; ++j) {                 // j = k*32 + h
    int k = j >> 5, hh = j & 31;
    float v = (k == 0) ? zst[zbase + (size_t)hh * 4096 + n]
                       : b2f(zsht[zshbase + (size_t)hh * 8192 + (size_t)(k - 1) * 4096 + n]);
#pragma unroll
    for (int q = 0; q < 8; ++q) acc[q] += (*(const f32x4*)&Wc[j][q * 4]) * v;
  }
  f32x4 y[8];
#pragma unroll
  for (int q = 0; q < 8; ++q)
#pragma unroll
    for (int c = 0; c < 4; ++c) y[q][c] = tanh_f(acc[q][c] + boutL[q * 4 + c]);

  f32x4 o0 = { b2L[0], b2L[1], b2L[2], b2L[3] };
  f32x4 o1 = { b2L[4], b2L[5], b2L[6], b2L[7] };
  for (int r1 = 0; r1 < 64; ++r1) {
    f32x4 p = y[0] * (*(const f32x4*)&W1L[r1][0]);
#pragma unroll
    for (int q = 1; q < 8; ++q) p += y[q] * (*(const f32x4*)&W1L[r1][q * 4]);
    float hv = b1L[r1] + p[0] + p[1] + p[2] + p[3];
    hv = fmaxf(hv, 0.f);
    o0 += (*(const f32x4*)&W2L[r1][0]) * hv;
    o1 += (*(const f32x4*)&W2L[r1][4]) * hv;
  }
  const size_t obase = ((size_t)b * 64 + tau) * 8 * 4096 + n;
#pragma unroll
  for (int r = 0; r < 4; ++r) {
    out[obase + (size_t)r * 4096]       = o0[r];
    out[obase + (size_t)(4 + r) * 4096] = o1[r];
  }
}

// ---------- host ----------
extern "C" void kernel_launch(void* const* d_in, const int* in_sizes, int n_in,
                              void* d_out, int out_size, void* d_ws, size_t ws_size,
                              hipStream_t stream) {
  const float* x    = (const float*)d_in[0];
  const float* z0   = (const float*)d_in[1];
  const float* S    = (const float*)d_in[2];
  const float* Af   = (const float*)d_in[3];
  const float* Bw   = (const float*)d_in[4];
  const float* bz   = (const float*)d_in[5];
  const float* Ca   = (const float*)d_in[6];
  const float* Cb   = (const float*)d_in[7];
  const float* bc   = (const float*)d_in[8];
  const float* Da   = (const float*)d_in[9];
  const float* Db   = (const float*)d_in[10];
  const float* bd   = (const float*)d_in[11];
  const float* Wout = (const float*)d_in[12];
  const float* bo   = (const float*)d_in[13];
  const float* W1   = (const float*)d_in[14];
  const float* b1   = (const float*)d_in[15];
  const float* W2   = (const float*)d_in[16];
  const float* b2   = (const float*)d_in[17];
  float* out = (float*)d_out;

  // workspace layout (~148 MiB)
  char* w = (char*)d_ws;
  short* Scat = (short*)w; w += (size_t)8192 * 4096 * 2;   // bf16 [S ; S^2] rows     67.1 MB
  short* xsh  = (short*)w; w += (size_t)4096 * 8192 * 2;   // bf16 x shifts (tmp S^T) 67.1 MB
  float* zbuf = (float*)w; w += (size_t)2 * 1048576 * 4;   // fp32 z ping-pong         8.4 MB
  short* zsh  = (short*)w; w += (size_t)2097152 * 2;       // bf16 z shifts 256x8192   4.2 MB
  float* zab  = (float*)w; w += (size_t)2 * 1048576 * 4;   // fp32 za,zb               8.4 MB
  float* gacc = (float*)w; w += 256;
  size_t need = (size_t)(w - (char*)d_ws);
  if (ws_size < need) {
    fprintf(stderr, "kernel_launch: WS TOO SMALL need=%zu have=%zu -- NOT LAUNCHING\n",
            need, ws_size);
    return;
  }

  short* STt = xsh;  // temp: bf16 S^T (dead before xsh GEMM writes)

  conv_k<<<8192, 256, 0, stream>>>(S, Scat, 2097152);          // bf16(S) -> Scat rows 0..4095
  hipMemcpyAsync(zbuf, z0, (size_t)1048576 * 4, hipMemcpyDeviceToDevice, stream);
  transpose_k<<<dim3(128, 128), dim3(32, 8), 0, stream>>>(S, STt);
  // S2 = bf16(S) * (S^T)^T -> rows 4096..8191 of Scat
  gemm_bt<0><<<dim3(32, 32), 256, 0, stream>>>(Scat, STt, Scat + (size_t)4096 * 4096, 4096, 4096);
  // x shifts: (B*T*F=4096 rows, fp32) x [S|S2]^T
  gemm_bt<1><<<dim3(64, 32), 256, 0, stream>>>(x, Scat, xsh, 4096, 8192);

  for (int t = 0; t <= 64; ++t) {
    float* zcur = zbuf + (size_t)(t & 1) * 1048576;
    float* znxt = zbuf + (size_t)((t + 1) & 1) * 1048576;
    // shifts of z_t: [S z_t ; S^2 z_t] -> zsh (256 x 8192), A is fp32
    gemm_bt<1><<<dim3(64, 2), 256, 0, stream>>>(zcur, Scat, zsh, 4096, 8192);
    if (t >= 1)  // output time index tau = t-1 uses z_t
      out_kernel<<<dim3(16, 8), 256, 0, stream>>>(zcur, zsh, Wout, bo, W1, b1, W2, b2, out, t - 1);
    if (t < 64) {
      hipMemsetAsync(gacc, 0, 64, stream);
      gate_kernel<<<512, 256, 0, stream>>>(x, xsh, zcur, zsh,
                                           Ca, Cb, bc, Da, Db, bd, Af, Bw, zab, gacc, t);
      update_kernel<<<512, 256, 0, stream>>>(zab, gacc, bz, znxt);
    }
  }
}

// Round 6
// 9629.090 us; speedup vs baseline: 1.3112x; 1.3112x over previous
//
#include <hip/hip_runtime.h>
#include <hip/hip_bf16.h>
#include <cstdio>

// ---------- types / helpers ----------
typedef __attribute__((ext_vector_type(4))) float f32x4;
typedef __attribute__((ext_vector_type(8))) short bf16x8;  // 8 bf16 raw

__device__ __forceinline__ short f2b(float f) {
  unsigned u = __builtin_bit_cast(unsigned, f);
  unsigned r = (u + 0x7FFFu + ((u >> 16) & 1u)) >> 16;  // RNE
  return (short)r;
}
__device__ __forceinline__ float b2f(short s) {
  union { unsigned u; float f; } c;
  c.u = ((unsigned)(unsigned short)s) << 16;
  return c.f;
}
__device__ __forceinline__ float sigm(float x) { return 1.f / (1.f + __expf(-x)); }
__device__ __forceinline__ float tanh_f(float x) {
  float e = __expf(2.f * x);
  return 1.f - 2.f / (e + 1.f);
}

// Problem dims: B=8 T=64 F=8 N=4096 H=32 G=32 K1=K2=3 R1=64 R2=8

// ---------- fp32 -> bf16 convert (8 elements per thread) ----------
__global__ void conv_k(const float* __restrict__ in, short* __restrict__ out, int n8) {
  int i = blockIdx.x * 256 + threadIdx.x;
  if (i >= n8) return;
  size_t base = (size_t)i * 8;
  f32x4 a = *(const f32x4*)(in + base), b = *(const f32x4*)(in + base + 4);
  bf16x8 v;
#pragma unroll
  for (int j = 0; j < 4; ++j) { v[j] = f2b(a[j]); v[4 + j] = f2b(b[j]); }
  *(bf16x8*)(out + base) = v;
}

// ---------- transpose+convert (fp32 4096x4096 -> bf16): out[p][m] = in[m][p] ----------
__global__ void transpose_k(const float* __restrict__ in, short* __restrict__ out) {
  __shared__ float tile[32][33];
  int bx = blockIdx.x * 32, by = blockIdx.y * 32;
  int tx = threadIdx.x, ty = threadIdx.y;
  for (int i = ty; i < 32; i += 8)
    tile[i][tx] = in[(size_t)(by + i) * 4096 + bx + tx];
  __syncthreads();
  for (int i = ty; i < 32; i += 8)
    out[(size_t)(bx + i) * 4096 + by + tx] = f2b(tile[tx][i]);
}

// ---------- preamble GEMM: C[M][N] = A[M][K] * Bt[N][K]^T, C bf16, fp32 accum ----------
// AF32: A fp32 converted during staging. grid (N/128, M/128), block 256.
template <int AF32>
__global__ __launch_bounds__(256) void gemm_pre(const void* __restrict__ Av,
                                                const short* __restrict__ Bt,
                                                short* __restrict__ C,
                                                int K, int ldc) {
  __shared__ __align__(16) short As[128][72];
  __shared__ __align__(16) short Bs[128][72];
  const int tid = threadIdx.x;
  const int lane = tid & 63, wave = tid >> 6;
  const int wm = wave >> 1, wn = wave & 1;
  const size_t m0 = (size_t)blockIdx.y * 128, n0 = (size_t)blockIdx.x * 128;
  const int r16 = lane & 15, g4 = lane >> 4;

  f32x4 acc[4][4];
#pragma unroll
  for (int mi = 0; mi < 4; ++mi)
#pragma unroll
    for (int ni = 0; ni < 4; ++ni) acc[mi][ni] = (f32x4)0.f;

  for (int kt = 0; kt < K; kt += 64) {
#pragma unroll
    for (int r = 0; r < 4; ++r) {
      int idx = r * 256 + tid;
      int row = idx >> 3;
      int kin = (idx & 7) * 8;
      if (AF32) {
        const float* A = (const float*)Av;
        const float* p = &A[(m0 + row) * (size_t)K + kt + kin];
        f32x4 a = *(const f32x4*)p, b = *(const f32x4*)(p + 4);
        bf16x8 v;
#pragma unroll
        for (int j = 0; j < 4; ++j) { v[j] = f2b(a[j]); v[4 + j] = f2b(b[j]); }
        *(bf16x8*)&As[row][kin] = v;
      } else {
        const short* A = (const short*)Av;
        *(bf16x8*)&As[row][kin] = *(const bf16x8*)&A[(m0 + row) * (size_t)K + kt + kin];
      }
      *(bf16x8*)&Bs[row][kin] = *(const bf16x8*)&Bt[(n0 + row) * (size_t)K + kt + kin];
    }
    __syncthreads();
#pragma unroll
    for (int ks = 0; ks < 2; ++ks) {
      bf16x8 af[4], bfr[4];
#pragma unroll
      for (int i = 0; i < 4; ++i) {
        af[i]  = *(const bf16x8*)&As[wm * 64 + i * 16 + r16][ks * 32 + g4 * 8];
        bfr[i] = *(const bf16x8*)&Bs[wn * 64 + i * 16 + r16][ks * 32 + g4 * 8];
      }
#pragma unroll
      for (int mi = 0; mi < 4; ++mi)
#pragma unroll
        for (int ni = 0; ni < 4; ++ni)
          acc[mi][ni] = __builtin_amdgcn_mfma_f32_16x16x32_bf16(af[mi], bfr[ni], acc[mi][ni], 0, 0, 0);
    }
    __syncthreads();
  }
#pragma unroll
  for (int mi = 0; mi < 4; ++mi) {
#pragma unroll
    for (int ni = 0; ni < 4; ++ni) {
      size_t row0 = m0 + wm * 64 + mi * 16 + g4 * 4;
      size_t col  = n0 + wn * 64 + ni * 16 + r16;
#pragma unroll
      for (int r = 0; r < 4; ++r)
        C[(row0 + r) * (size_t)ldc + col] = f2b(acc[mi][ni][r]);
    }
  }
}

// ---------- per-step z-shift GEMM, split-K ----------
// P[ks][r][n] (fp32), r=b*32+h (256), n in [0,8192) = [tap1 | tap2].
// grid (128 n-tiles of 64, 2 m-tiles of 128, 2 K-splits of 2048), block 256.
__global__ __launch_bounds__(256) void gemm_zsh(const short* __restrict__ z,
                                                const short* __restrict__ Scat,
                                                float* __restrict__ P) {
  __shared__ __align__(16) short As[128][72];
  __shared__ __align__(16) short Bs[64][72];
  const int tid = threadIdx.x, lane = tid & 63, wave = tid >> 6;
  const int wm = wave >> 1, wn = wave & 1;      // 2m x 2n waves, each 64x32
  const int m0 = blockIdx.y * 128, n0 = blockIdx.x * 64;
  const int kt0 = blockIdx.z * 2048;
  const int r16 = lane & 15, g4 = lane >> 4;
  f32x4 acc[4][2];
#pragma unroll
  for (int mi = 0; mi < 4; ++mi)
#pragma unroll
    for (int ni = 0; ni < 2; ++ni) acc[mi][ni] = (f32x4)0.f;

  for (int kt = kt0; kt < kt0 + 2048; kt += 64) {
#pragma unroll
    for (int r = 0; r < 4; ++r) {
      int idx = r * 256 + tid, row = idx >> 3, kin = (idx & 7) * 8;
      *(bf16x8*)&As[row][kin] = *(const bf16x8*)&z[(size_t)(m0 + row) * 4096 + kt + kin];
    }
#pragma unroll
    for (int r = 0; r < 2; ++r) {
      int idx = r * 256 + tid, row = idx >> 3, kin = (idx & 7) * 8;
      *(bf16x8*)&Bs[row][kin] = *(const bf16x8*)&Scat[(size_t)(n0 + row) * 4096 + kt + kin];
    }
    __syncthreads();
#pragma unroll
    for (int ks = 0; ks < 2; ++ks) {
      bf16x8 af[4], bfr[2];
#pragma unroll
      for (int i = 0; i < 4; ++i) af[i]  = *(const bf16x8*)&As[wm * 64 + i * 16 + r16][ks * 32 + g4 * 8];
#pragma unroll
      for (int i = 0; i < 2; ++i) bfr[i] = *(const bf16x8*)&Bs[wn * 32 + i * 16 + r16][ks * 32 + g4 * 8];
#pragma unroll
      for (int mi = 0; mi < 4; ++mi)
#pragma unroll
        for (int ni = 0; ni < 2; ++ni)
          acc[mi][ni] = __builtin_amdgcn_mfma_f32_16x16x32_bf16(af[mi], bfr[ni], acc[mi][ni], 0, 0, 0);
    }
    __syncthreads();
  }
  float* Pz = P + (size_t)blockIdx.z * 2097152;
#pragma unroll
  for (int mi = 0; mi < 4; ++mi)
#pragma unroll
    for (int ni = 0; ni < 2; ++ni) {
      int row0 = m0 + wm * 64 + mi * 16 + g4 * 4;
      int col  = n0 + wn * 32 + ni * 16 + r16;
#pragma unroll
      for (int r = 0; r < 4; ++r)
        Pz[(size_t)(row0 + r) * 8192 + col] = acc[mi][ni][r];
    }
}

// ---------- fused gate (blocks 0..511) + output stage (blocks 512..639) ----------
// Taps: k=0 -> bf16 z_t; k=1,2 -> P0+P1 (fp32 split-K partials).
// gate: b = bid>>6, 64-n chunk = bid&63, 256 thr = 64 n x 4 h-groups.
// out (tau=t-1): b = (bid-512)>>4, 256-n chunk = (bid-512)&15.
__global__ __launch_bounds__(256) void gateout_kernel(
    const float* __restrict__ x, const short* __restrict__ xsh,
    const short* __restrict__ zt, const float* __restrict__ P,
    const float* __restrict__ Ca, const float* __restrict__ Cb, const float* __restrict__ bc,
    const float* __restrict__ Da, const float* __restrict__ Db, const float* __restrict__ bd,
    const float* __restrict__ Af, const float* __restrict__ Bw,
    const float* __restrict__ Wout, const float* __restrict__ bout,
    const float* __restrict__ W1, const float* __restrict__ b1,
    const float* __restrict__ W2, const float* __restrict__ b2,
    float* __restrict__ zab, float* __restrict__ gacc,
    float* __restrict__ out, int t) {
  __shared__ __align__(16) float sm[11840];
  const int tid = threadIdx.x;
  const int bid = blockIdx.x;

  if (bid < 512) {
    if (t >= 64) return;
    float* Fu  = sm;            // [120][32]
    float* Fd  = sm + 3840;     // [120][32]
    float* Fb  = sm + 7680;     // [96][32]
    float* Fa  = sm + 10752;    // [24][32]
    float* bcs = sm + 11520;    // [32]
    float* bds = sm + 11552;    // [32]
    float* red = sm + 11584;    // [8]
    for (int i = tid; i < 120 * 32; i += 256) {
      int j = i >> 5, h = i & 31;
      float fu, fd;
      if (j < 96) { int k = j >> 5, hh = j & 31;
        fu = Cb[(h * 3 + k) * 32 + hh]; fd = Db[(h * 3 + k) * 32 + hh]; }
      else { int jj = j - 96, k = jj >> 3, f = jj & 7;
        fu = Ca[(h * 3 + k) * 8 + f];  fd = Da[(h * 3 + k) * 8 + f]; }
      Fu[j * 32 + h] = fu; Fd[j * 32 + h] = fd;
    }
    for (int i = tid; i < 96 * 32; i += 256) { int j = i >> 5, h = i & 31; int k = j >> 5, hh = j & 31;
      Fb[j * 32 + h] = Bw[(h * 3 + k) * 32 + hh]; }
    for (int i = tid; i < 24 * 32; i += 256) { int j = i >> 5, h = i & 31; int k = j >> 3, f = j & 7;
      Fa[j * 32 + h] = Af[(h * 3 + k) * 8 + f]; }
    if (tid < 32) { bcs[tid] = bc[tid]; bds[tid] = bd[tid]; }
    __syncthreads();

    const int b = bid >> 6, chunk = bid & 63;
    const int nn = tid & 63, hg = tid >> 6, h0 = hg * 8;
    const int n = chunk * 64 + nn;
    const size_t zrow = (size_t)b * 32;

    f32x4 guA = *(const f32x4*)&bcs[h0], guB = *(const f32x4*)&bcs[h0 + 4];
    f32x4 gdA = *(const f32x4*)&bds[h0], gdB = *(const f32x4*)&bds[h0 + 4];
    f32x4 zaA = (f32x4)0.f, zaB = (f32x4)0.f, zbA = (f32x4)0.f, zbB = (f32x4)0.f;

    for (int j = 0; j < 96; ++j) {                 // z taps: j = k*32 + h'
      int k = j >> 5, hh = j & 31;
      float v;
      if (k == 0) v = b2f(zt[(zrow + hh) * 4096 + n]);
      else { size_t off = (zrow + hh) * 8192 + (size_t)(k - 1) * 4096 + n;
        v = P[off] + P[2097152 + off]; }
      f32x4 u0 = *(const f32x4*)&Fu[j * 32 + h0], u1 = *(const f32x4*)&Fu[j * 32 + h0 + 4];
      f32x4 d0 = *(const f32x4*)&Fd[j * 32 + h0], d1 = *(const f32x4*)&Fd[j * 32 + h0 + 4];
      f32x4 p0 = *(const f32x4*)&Fb[j * 32 + h0], p1 = *(const f32x4*)&Fb[j * 32 + h0 + 4];
      guA += u0 * v; guB += u1 * v; gdA += d0 * v; gdB += d1 * v; zbA += p0 * v; zbB += p1 * v;
    }
    const size_t xrow = ((size_t)b * 64 + t) * 8;
    for (int j = 0; j < 24; ++j) {                 // x taps: j = k*8 + f
      int k = j >> 3, f = j & 7;
      float v = (k == 0) ? x[(xrow + f) * 4096 + n]
                         : b2f(xsh[(xrow + f) * 8192 + (size_t)(k - 1) * 4096 + n]);
      f32x4 u0 = *(const f32x4*)&Fu[(96 + j) * 32 + h0], u1 = *(const f32x4*)&Fu[(96 + j) * 32 + h0 + 4];
      f32x4 d0 = *(const f32x4*)&Fd[(96 + j) * 32 + h0], d1 = *(const f32x4*)&Fd[(96 + j) * 32 + h0 + 4];
      f32x4 a0 = *(const f32x4*)&Fa[j * 32 + h0],        a1 = *(const f32x4*)&Fa[j * 32 + h0 + 4];
      guA += u0 * v; guB += u1 * v; gdA += d0 * v; gdB += d1 * v; zaA += a0 * v; zaB += a1 * v;
    }

    float su = 0.f, sd = 0.f;
#pragma unroll
    for (int i = 0; i < 4; ++i) {
      su += sigm(guA[i]) + sigm(guB[i]);
      sd += sigm(gdA[i]) + sigm(gdB[i]);
      zab[(zrow + h0 + i) * 4096 + n]               = zaA[i];
      zab[(zrow + h0 + 4 + i) * 4096 + n]           = zaB[i];
      zab[1048576 + (zrow + h0 + i) * 4096 + n]     = zbA[i];
      zab[1048576 + (zrow + h0 + 4 + i) * 4096 + n] = zbB[i];
    }
    for (int off = 32; off; off >>= 1) { su += __shfl_down(su, off); sd += __shfl_down(sd, off); }
    const int wv = tid >> 6;
    if ((tid & 63) == 0) { red[wv] = su; red[4 + wv] = sd; }
    __syncthreads();
    if (tid == 0) {
      const int par = t & 1;
      atomicAdd(&gacc[par * 16 + b],     red[0] + red[1] + red[2] + red[3]);
      atomicAdd(&gacc[par * 16 + 8 + b], red[4] + red[5] + red[6] + red[7]);
    }
  } else {
    if (t < 1) return;
    const int tau = t - 1;
    float* Wc    = sm;          // [96][32]
    float* W1L   = sm + 3072;   // [64][32]
    float* W2L   = sm + 5120;   // [64][8]
    float* boutL = sm + 5632;   // [32]
    float* b1L   = sm + 5664;   // [64]
    float* b2L   = sm + 5728;   // [8]
    for (int i = tid; i < 96 * 32; i += 256) { int j = i >> 5, g = i & 31; int k = j >> 5, hh = j & 31;
      Wc[j * 32 + g] = Wout[(g * 3 + k) * 32 + hh]; }
    for (int i = tid; i < 64 * 32; i += 256) { int r1 = i >> 5, g = i & 31; W1L[r1 * 32 + g] = W1[r1 * 32 + g]; }
    for (int i = tid; i < 512; i += 256) { int r1 = i >> 3, r = i & 7; W2L[r1 * 8 + r] = W2[r * 64 + r1]; }
    if (tid < 32) boutL[tid] = bout[tid];
    if (tid < 64) b1L[tid] = b1[tid];
    if (tid < 8)  b2L[tid] = b2[tid];
    __syncthreads();

    const int bo2 = bid - 512;
    const int b = bo2 >> 4, chunk = bo2 & 15;
    const int n = chunk * 256 + tid;
    const size_t zbase = (size_t)b * 32;

    f32x4 acc[8];
#pragma unroll
    for (int q = 0; q < 8; ++q) acc[q] = (f32x4)0.f;
    for (int j = 0; j < 96; ++j) {
      int k = j >> 5, hh = j & 31;
      float v;
      if (k == 0) v = b2f(zt[(zbase + hh) * 4096 + n]);
      else { size_t off = (zbase + hh) * 8192 + (size_t)(k - 1) * 4096 + n;
        v = P[off] + P[2097152 + off]; }
#pragma unroll
      for (int q = 0; q < 8; ++q) acc[q] += (*(const f32x4*)&Wc[j * 32 + q * 4]) * v;
    }
    f32x4 y[8];
#pragma unroll
    for (int q = 0; q < 8; ++q)
#pragma unroll
      for (int c = 0; c < 4; ++c) y[q][c] = tanh_f(acc[q][c] + boutL[q * 4 + c]);

    f32x4 o0 = { b2L[0], b2L[1], b2L[2], b2L[3] };
    f32x4 o1 = { b2L[4], b2L[5], b2L[6], b2L[7] };
    for (int r1 = 0; r1 < 64; ++r1) {
      f32x4 p = y[0] * (*(const f32x4*)&W1L[r1 * 32]);
#pragma unroll
      for (int q = 1; q < 8; ++q) p += y[q] * (*(const f32x4*)&W1L[r1 * 32 + q * 4]);
      float hv = b1L[r1] + p[0] + p[1] + p[2] + p[3];
      hv = fmaxf(hv, 0.f);
      o0 += (*(const f32x4*)&W2L[r1 * 8]) * hv;
      o1 += (*(const f32x4*)&W2L[r1 * 8 + 4]) * hv;
    }
    const size_t obase = ((size_t)b * 64 + tau) * 8 * 4096 + n;
#pragma unroll
    for (int r = 0; r < 4; ++r) {
      out[obase + (size_t)r * 4096]       = o0[r];
      out[obase + (size_t)(4 + r) * 4096] = o1[r];
    }
  }
}

// ---------- per-step state update (bf16 z out) + zero next parity gacc ----------
__global__ __launch_bounds__(256) void update_kernel(
    const float* __restrict__ zab, float* __restrict__ gacc,
    const float* __restrict__ bz, short* __restrict__ zout, int t) {
  const int par = t & 1;
  if (blockIdx.x == 0 && threadIdx.x < 16) gacc[(par ^ 1) * 16 + threadIdx.x] = 0.f;
  size_t idx = (size_t)blockIdx.x * 256 + threadIdx.x;   // 131072 threads
  size_t base = idx * 8;
  int row = (int)(base >> 12);
  int b = row >> 5, h = row & 31;
  float u  = gacc[par * 16 + b]     * (1.f / 131072.f);
  float fg = gacc[par * 16 + 8 + b] * (1.f / 131072.f);
  float bzv = bz[h];
  f32x4 za0 = *(const f32x4*)(zab + base),           za1 = *(const f32x4*)(zab + base + 4);
  f32x4 zb0 = *(const f32x4*)(zab + 1048576 + base), zb1 = *(const f32x4*)(zab + 1048576 + base + 4);
  bf16x8 ov;
#pragma unroll
  for (int i = 0; i < 4; ++i) {
    ov[i]     = f2b(tanh_f(u * za0[i] + fg * zb0[i] + bzv));
    ov[4 + i] = f2b(tanh_f(u * za1[i] + fg * zb1[i] + bzv));
  }
  *(bf16x8*)(zout + base) = ov;
}

// ---------- host ----------
extern "C" void kernel_launch(void* const* d_in, const int* in_sizes, int n_in,
                              void* d_out, int out_size, void* d_ws, size_t ws_size,
                              hipStream_t stream) {
  const float* x    = (const float*)d_in[0];
  const float* z0   = (const float*)d_in[1];
  const float* S    = (const float*)d_in[2];
  const float* Af   = (const float*)d_in[3];
  const float* Bw   = (const float*)d_in[4];
  const float* bz   = (const float*)d_in[5];
  const float* Ca   = (const float*)d_in[6];
  const float* Cb   = (const float*)d_in[7];
  const float* bc   = (const float*)d_in[8];
  const float* Da   = (const float*)d_in[9];
  const float* Db   = (const float*)d_in[10];
  const float* bd   = (const float*)d_in[11];
  const float* Wout = (const float*)d_in[12];
  const float* bo   = (const float*)d_in[13];
  const float* W1   = (const float*)d_in[14];
  const float* b1   = (const float*)d_in[15];
  const float* W2   = (const float*)d_in[16];
  const float* b2   = (const float*)d_in[17];
  float* out = (float*)d_out;

  // workspace layout (~163.6 MiB)
  char* w = (char*)d_ws;
  short* Scat = (short*)w; w += (size_t)8192 * 4096 * 2;   // bf16 [S ; S^2]          67.1 MB
  short* xsh  = (short*)w; w += (size_t)4096 * 8192 * 2;   // bf16 x shifts (tmp S^T) 67.1 MB
  short* zbuf = (short*)w; w += (size_t)2 * 1048576 * 2;   // bf16 z ping-pong         4.2 MB
  float* P    = (float*)w; w += (size_t)2 * 2097152 * 4;   // fp32 split-K partials   16.8 MB
  float* zab  = (float*)w; w += (size_t)2 * 1048576 * 4;   // fp32 za,zb               8.4 MB
  float* gacc = (float*)w; w += 256;                       // 2 parities x 16 floats
  size_t need = (size_t)(w - (char*)d_ws);
  if (ws_size < need) {
    fprintf(stderr, "kernel_launch: WS TOO SMALL need=%zu have=%zu -- NOT LAUNCHING\n",
            need, ws_size);
    return;
  }

  short* STt = xsh;  // temp: bf16 S^T (consumed by S^2 GEMM before xsh is written)

  conv_k<<<512, 256, 0, stream>>>(z0, zbuf, 131072);            // bf16 z_0
  conv_k<<<8192, 256, 0, stream>>>(S, Scat, 2097152);           // bf16 S
  transpose_k<<<dim3(128, 128), dim3(32, 8), 0, stream>>>(S, STt);
  gemm_pre<0><<<dim3(32, 32), 256, 0, stream>>>(Scat, STt, Scat + (size_t)4096 * 4096, 4096, 4096);
  gemm_pre<1><<<dim3(64, 32), 256, 0, stream>>>(x, Scat, xsh, 4096, 8192);
  hipMemsetAsync(gacc, 0, 128, stream);

  for (int t = 0; t <= 64; ++t) {
    short* zcur = zbuf + (size_t)(t & 1) * 1048576;
    short* znxt = zbuf + (size_t)((t + 1) & 1) * 1048576;
    gemm_zsh<<<dim3(128, 2, 2), 256, 0, stream>>>(zcur, Scat, P);
    gateout_kernel<<<640, 256, 0, stream>>>(x, xsh, zcur, P,
                                            Ca, Cb, bc, Da, Db, bd, Af, Bw,
                                            Wout, bo, W1, b1, W2, b2,
                                            zab, gacc, out, t);
    if (t < 64)
      update_kernel<<<512, 256, 0, stream>>>(zab, gacc, bz, znxt, t);
  }
}

// Round 7
// 9518.821 us; speedup vs baseline: 1.3264x; 1.0116x over previous
//
#include <hip/hip_runtime.h>
#include <hip/hip_bf16.h>
#include <cstdio>

// ---------- types / helpers ----------
typedef __attribute__((ext_vector_type(4))) float f32x4;
typedef __attribute__((ext_vector_type(8))) short bf16x8;  // 8 bf16 raw

__device__ __forceinline__ short f2b(float f) {
  unsigned u = __builtin_bit_cast(unsigned, f);
  unsigned r = (u + 0x7FFFu + ((u >> 16) & 1u)) >> 16;  // RNE
  return (short)r;
}
__device__ __forceinline__ float b2f(short s) {
  union { unsigned u; float f; } c;
  c.u = ((unsigned)(unsigned short)s) << 16;
  return c.f;
}
__device__ __forceinline__ float sigm(float x) { return 1.f / (1.f + __expf(-x)); }
__device__ __forceinline__ float tanh_f(float x) {
  float e = __expf(2.f * x);
  return 1.f - 2.f / (e + 1.f);
}

// Problem dims: B=8 T=64 F=8 N=4096 H=32 G=32 K1=K2=3 R1=64 R2=8

// ---------- fp32 -> bf16 convert (8 elements per thread) ----------
__global__ void conv_k(const float* __restrict__ in, short* __restrict__ out, int n8) {
  int i = blockIdx.x * 256 + threadIdx.x;
  if (i >= n8) return;
  size_t base = (size_t)i * 8;
  f32x4 a = *(const f32x4*)(in + base), b = *(const f32x4*)(in + base + 4);
  bf16x8 v;
#pragma unroll
  for (int j = 0; j < 4; ++j) { v[j] = f2b(a[j]); v[4 + j] = f2b(b[j]); }
  *(bf16x8*)(out + base) = v;
}

// ---------- transpose+convert (fp32 4096x4096 -> bf16): out[p][m] = in[m][p] ----------
__global__ void transpose_k(const float* __restrict__ in, short* __restrict__ out) {
  __shared__ float tile[32][33];
  int bx = blockIdx.x * 32, by = blockIdx.y * 32;
  int tx = threadIdx.x, ty = threadIdx.y;
  for (int i = ty; i < 32; i += 8)
    tile[i][tx] = in[(size_t)(by + i) * 4096 + bx + tx];
  __syncthreads();
  for (int i = ty; i < 32; i += 8)
    out[(size_t)(bx + i) * 4096 + by + tx] = f2b(tile[tx][i]);
}

// ---------- preamble GEMM: C[M][N] = A[M][K] * Bt[N][K]^T, C bf16, fp32 accum ----------
// AF32: A fp32 converted during staging. grid (N/128, M/128), block 256.
template <int AF32>
__global__ __launch_bounds__(256) void gemm_pre(const void* __restrict__ Av,
                                                const short* __restrict__ Bt,
                                                short* __restrict__ C,
                                                int K, int ldc) {
  __shared__ __align__(16) short As[128][72];
  __shared__ __align__(16) short Bs[128][72];
  const int tid = threadIdx.x;
  const int lane = tid & 63, wave = tid >> 6;
  const int wm = wave >> 1, wn = wave & 1;
  const size_t m0 = (size_t)blockIdx.y * 128, n0 = (size_t)blockIdx.x * 128;
  const int r16 = lane & 15, g4 = lane >> 4;

  f32x4 acc[4][4];
#pragma unroll
  for (int mi = 0; mi < 4; ++mi)
#pragma unroll
    for (int ni = 0; ni < 4; ++ni) acc[mi][ni] = (f32x4)0.f;

  for (int kt = 0; kt < K; kt += 64) {
#pragma unroll
    for (int r = 0; r < 4; ++r) {
      int idx = r * 256 + tid;
      int row = idx >> 3;
      int kin = (idx & 7) * 8;
      if (AF32) {
        const float* A = (const float*)Av;
        const float* p = &A[(m0 + row) * (size_t)K + kt + kin];
        f32x4 a = *(const f32x4*)p, b = *(const f32x4*)(p + 4);
        bf16x8 v;
#pragma unroll
        for (int j = 0; j < 4; ++j) { v[j] = f2b(a[j]); v[4 + j] = f2b(b[j]); }
        *(bf16x8*)&As[row][kin] = v;
      } else {
        const short* A = (const short*)Av;
        *(bf16x8*)&As[row][kin] = *(const bf16x8*)&A[(m0 + row) * (size_t)K + kt + kin];
      }
      *(bf16x8*)&Bs[row][kin] = *(const bf16x8*)&Bt[(n0 + row) * (size_t)K + kt + kin];
    }
    __syncthreads();
#pragma unroll
    for (int ks = 0; ks < 2; ++ks) {
      bf16x8 af[4], bfr[4];
#pragma unroll
      for (int i = 0; i < 4; ++i) {
        af[i]  = *(const bf16x8*)&As[wm * 64 + i * 16 + r16][ks * 32 + g4 * 8];
        bfr[i] = *(const bf16x8*)&Bs[wn * 64 + i * 16 + r16][ks * 32 + g4 * 8];
      }
#pragma unroll
      for (int mi = 0; mi < 4; ++mi)
#pragma unroll
        for (int ni = 0; ni < 4; ++ni)
          acc[mi][ni] = __builtin_amdgcn_mfma_f32_16x16x32_bf16(af[mi], bfr[ni], acc[mi][ni], 0, 0, 0);
    }
    __syncthreads();
  }
#pragma unroll
  for (int mi = 0; mi < 4; ++mi) {
#pragma unroll
    for (int ni = 0; ni < 4; ++ni) {
      size_t row0 = m0 + wm * 64 + mi * 16 + g4 * 4;
      size_t col  = n0 + wn * 64 + ni * 16 + r16;
#pragma unroll
      for (int r = 0; r < 4; ++r)
        C[(row0 + r) * (size_t)ldc + col] = f2b(acc[mi][ni][r]);
    }
  }
}

// ---------- per-step z-shift GEMM: BM=256 (all rows), BN=64, full K ----------
// zsh[r][n] bf16, r=b*32+h (256), n in [0,8192) = [tap1 | tap2].
// grid 128 (n-tiles of 64), block 256 = 4 waves; each wave 64 rows x 64 cols.
__global__ __launch_bounds__(256) void gemm_zsh256(const short* __restrict__ z,
                                                   const short* __restrict__ Scat,
                                                   short* __restrict__ zsh) {
  __shared__ __align__(16) short As[256][72];
  __shared__ __align__(16) short Bs[64][72];
  const int tid = threadIdx.x, lane = tid & 63, wave = tid >> 6;
  const int n0 = blockIdx.x * 64;
  const int r16 = lane & 15, g4 = lane >> 4;
  f32x4 acc[4][4];
#pragma unroll
  for (int mi = 0; mi < 4; ++mi)
#pragma unroll
    for (int ni = 0; ni < 4; ++ni) acc[mi][ni] = (f32x4)0.f;

  for (int kt = 0; kt < 4096; kt += 64) {
#pragma unroll
    for (int r = 0; r < 8; ++r) {                 // A: 256 rows x 64 k
      int idx = r * 256 + tid, row = idx >> 3, kin = (idx & 7) * 8;
      *(bf16x8*)&As[row][kin] = *(const bf16x8*)&z[(size_t)row * 4096 + kt + kin];
    }
#pragma unroll
    for (int r = 0; r < 2; ++r) {                 // B: 64 rows x 64 k
      int idx = r * 256 + tid, row = idx >> 3, kin = (idx & 7) * 8;
      *(bf16x8*)&Bs[row][kin] = *(const bf16x8*)&Scat[(size_t)(n0 + row) * 4096 + kt + kin];
    }
    __syncthreads();
#pragma unroll
    for (int ks = 0; ks < 2; ++ks) {
      bf16x8 af[4], bfr[4];
#pragma unroll
      for (int i = 0; i < 4; ++i) {
        af[i]  = *(const bf16x8*)&As[wave * 64 + i * 16 + r16][ks * 32 + g4 * 8];
        bfr[i] = *(const bf16x8*)&Bs[i * 16 + r16][ks * 32 + g4 * 8];
      }
#pragma unroll
      for (int mi = 0; mi < 4; ++mi)
#pragma unroll
        for (int ni = 0; ni < 4; ++ni)
          acc[mi][ni] = __builtin_amdgcn_mfma_f32_16x16x32_bf16(af[mi], bfr[ni], acc[mi][ni], 0, 0, 0);
    }
    __syncthreads();
  }
#pragma unroll
  for (int mi = 0; mi < 4; ++mi)
#pragma unroll
    for (int ni = 0; ni < 4; ++ni) {
      int row0 = wave * 64 + mi * 16 + g4 * 4;
      int col  = n0 + ni * 16 + r16;
#pragma unroll
      for (int r = 0; r < 4; ++r)
        zsh[(size_t)(row0 + r) * 8192 + col] = f2b(acc[mi][ni][r]);
    }
}

// ---------- fused gate (blocks 0..511) + output stage (blocks 512..639) ----------
// Taps: k=0 -> bf16 z_t; k=1,2 -> bf16 zsh.
// gate: b = bid>>6, 64-n chunk = bid&63, 256 thr = 64 n x 4 h-groups.
// out (tau=t-1): b = (bid-512)>>4, 256-n chunk = (bid-512)&15.
__global__ __launch_bounds__(256) void gateout_kernel(
    const float* __restrict__ x, const short* __restrict__ xsh,
    const short* __restrict__ zt, const short* __restrict__ zsh,
    const float* __restrict__ Ca, const float* __restrict__ Cb, const float* __restrict__ bc,
    const float* __restrict__ Da, const float* __restrict__ Db, const float* __restrict__ bd,
    const float* __restrict__ Af, const float* __restrict__ Bw,
    const float* __restrict__ Wout, const float* __restrict__ bout,
    const float* __restrict__ W1, const float* __restrict__ b1,
    const float* __restrict__ W2, const float* __restrict__ b2,
    float* __restrict__ zab, float* __restrict__ gacc,
    float* __restrict__ out, int t) {
  __shared__ __align__(16) float sm[11840];
  const int tid = threadIdx.x;
  const int bid = blockIdx.x;

  if (bid < 512) {
    if (t >= 64) return;
    float* Fu  = sm;            // [120][32]
    float* Fd  = sm + 3840;     // [120][32]
    float* Fb  = sm + 7680;     // [96][32]
    float* Fa  = sm + 10752;    // [24][32]
    float* bcs = sm + 11520;    // [32]
    float* bds = sm + 11552;    // [32]
    float* red = sm + 11584;    // [8]
    for (int i = tid; i < 120 * 32; i += 256) {
      int j = i >> 5, h = i & 31;
      float fu, fd;
      if (j < 96) { int k = j >> 5, hh = j & 31;
        fu = Cb[(h * 3 + k) * 32 + hh]; fd = Db[(h * 3 + k) * 32 + hh]; }
      else { int jj = j - 96, k = jj >> 3, f = jj & 7;
        fu = Ca[(h * 3 + k) * 8 + f];  fd = Da[(h * 3 + k) * 8 + f]; }
      Fu[j * 32 + h] = fu; Fd[j * 32 + h] = fd;
    }
    for (int i = tid; i < 96 * 32; i += 256) { int j = i >> 5, h = i & 31; int k = j >> 5, hh = j & 31;
      Fb[j * 32 + h] = Bw[(h * 3 + k) * 32 + hh]; }
    for (int i = tid; i < 24 * 32; i += 256) { int j = i >> 5, h = i & 31; int k = j >> 3, f = j & 7;
      Fa[j * 32 + h] = Af[(h * 3 + k) * 8 + f]; }
    if (tid < 32) { bcs[tid] = bc[tid]; bds[tid] = bd[tid]; }
    __syncthreads();

    const int b = bid >> 6, chunk = bid & 63;
    const int nn = tid & 63, hg = tid >> 6, h0 = hg * 8;
    const int n = chunk * 64 + nn;
    const size_t zrow = (size_t)b * 32;

    f32x4 guA = *(const f32x4*)&bcs[h0], guB = *(const f32x4*)&bcs[h0 + 4];
    f32x4 gdA = *(const f32x4*)&bds[h0], gdB = *(const f32x4*)&bds[h0 + 4];
    f32x4 zaA = (f32x4)0.f, zaB = (f32x4)0.f, zbA = (f32x4)0.f, zbB = (f32x4)0.f;

    for (int j = 0; j < 96; ++j) {                 // z taps: j = k*32 + h'
      int k = j >> 5, hh = j & 31;
      float v = (k == 0) ? b2f(zt[(zrow + hh) * 4096 + n])
                         : b2f(zsh[(zrow + hh) * 8192 + (size_t)(k - 1) * 4096 + n]);
      f32x4 u0 = *(const f32x4*)&Fu[j * 32 + h0], u1 = *(const f32x4*)&Fu[j * 32 + h0 + 4];
      f32x4 d0 = *(const f32x4*)&Fd[j * 32 + h0], d1 = *(const f32x4*)&Fd[j * 32 + h0 + 4];
      f32x4 p0 = *(const f32x4*)&Fb[j * 32 + h0], p1 = *(const f32x4*)&Fb[j * 32 + h0 + 4];
      guA += u0 * v; guB += u1 * v; gdA += d0 * v; gdB += d1 * v; zbA += p0 * v; zbB += p1 * v;
    }
    const size_t xrow = ((size_t)b * 64 + t) * 8;
    for (int j = 0; j < 24; ++j) {                 // x taps: j = k*8 + f
      int k = j >> 3, f = j & 7;
      float v = (k == 0) ? x[(xrow + f) * 4096 + n]
                         : b2f(xsh[(xrow + f) * 8192 + (size_t)(k - 1) * 4096 + n]);
      f32x4 u0 = *(const f32x4*)&Fu[(96 + j) * 32 + h0], u1 = *(const f32x4*)&Fu[(96 + j) * 32 + h0 + 4];
      f32x4 d0 = *(const f32x4*)&Fd[(96 + j) * 32 + h0], d1 = *(const f32x4*)&Fd[(96 + j) * 32 + h0 + 4];
      f32x4 a0 = *(const f32x4*)&Fa[j * 32 + h0],        a1 = *(const f32x4*)&Fa[j * 32 + h0 + 4];
      guA += u0 * v; guB += u1 * v; gdA += d0 * v; gdB += d1 * v; zaA += a0 * v; zaB += a1 * v;
    }

    float su = 0.f, sd = 0.f;
#pragma unroll
    for (int i = 0; i < 4; ++i) {
      su += sigm(guA[i]) + sigm(guB[i]);
      sd += sigm(gdA[i]) + sigm(gdB[i]);
      zab[(zrow + h0 + i) * 4096 + n]               = zaA[i];
      zab[(zrow + h0 + 4 + i) * 4096 + n]           = zaB[i];
      zab[1048576 + (zrow + h0 + i) * 4096 + n]     = zbA[i];
      zab[1048576 + (zrow + h0 + 4 + i) * 4096 + n] = zbB[i];
    }
    for (int off = 32; off; off >>= 1) { su += __shfl_down(su, off); sd += __shfl_down(sd, off); }
    const int wv = tid >> 6;
    if ((tid & 63) == 0) { red[wv] = su; red[4 + wv] = sd; }
    __syncthreads();
    if (tid == 0) {
      const int par = t & 1;
      atomicAdd(&gacc[par * 16 + b],     red[0] + red[1] + red[2] + red[3]);
      atomicAdd(&gacc[par * 16 + 8 + b], red[4] + red[5] + red[6] + red[7]);
    }
  } else {
    if (t < 1) return;
    const int tau = t - 1;
    float* Wc    = sm;          // [96][32]
    float* W1L   = sm + 3072;   // [64][32]
    float* W2L   = sm + 5120;   // [64][8]
    float* boutL = sm + 5632;   // [32]
    float* b1L   = sm + 5664;   // [64]
    float* b2L   = sm + 5728;   // [8]
    for (int i = tid; i < 96 * 32; i += 256) { int j = i >> 5, g = i & 31; int k = j >> 5, hh = j & 31;
      Wc[j * 32 + g] = Wout[(g * 3 + k) * 32 + hh]; }
    for (int i = tid; i < 64 * 32; i += 256) { int r1 = i >> 5, g = i & 31; W1L[r1 * 32 + g] = W1[r1 * 32 + g]; }
    for (int i = tid; i < 512; i += 256) { int r1 = i >> 3, r = i & 7; W2L[r1 * 8 + r] = W2[r * 64 + r1]; }
    if (tid < 32) boutL[tid] = bout[tid];
    if (tid < 64) b1L[tid] = b1[tid];
    if (tid < 8)  b2L[tid] = b2[tid];
    __syncthreads();

    const int bo2 = bid - 512;
    const int b = bo2 >> 4, chunk = bo2 & 15;
    const int n = chunk * 256 + tid;
    const size_t zbase = (size_t)b * 32;

    f32x4 acc[8];
#pragma unroll
    for (int q = 0; q < 8; ++q) acc[q] = (f32x4)0.f;
    for (int j = 0; j < 96; ++j) {
      int k = j >> 5, hh = j & 31;
      float v = (k == 0) ? b2f(zt[(zbase + hh) * 4096 + n])
                         : b2f(zsh[(zbase + hh) * 8192 + (size_t)(k - 1) * 4096 + n]);
#pragma unroll
      for (int q = 0; q < 8; ++q) acc[q] += (*(const f32x4*)&Wc[j * 32 + q * 4]) * v;
    }
    f32x4 y[8];
#pragma unroll
    for (int q = 0; q < 8; ++q)
#pragma unroll
      for (int c = 0; c < 4; ++c) y[q][c] = tanh_f(acc[q][c] + boutL[q * 4 + c]);

    f32x4 o0 = { b2L[0], b2L[1], b2L[2], b2L[3] };
    f32x4 o1 = { b2L[4], b2L[5], b2L[6], b2L[7] };
    for (int r1 = 0; r1 < 64; ++r1) {
      f32x4 p = y[0] * (*(const f32x4*)&W1L[r1 * 32]);
#pragma unroll
      for (int q = 1; q < 8; ++q) p += y[q] * (*(const f32x4*)&W1L[r1 * 32 + q * 4]);
      float hv = b1L[r1] + p[0] + p[1] + p[2] + p[3];
      hv = fmaxf(hv, 0.f);
      o0 += (*(const f32x4*)&W2L[r1 * 8]) * hv;
      o1 += (*(const f32x4*)&W2L[r1 * 8 + 4]) * hv;
    }
    const size_t obase = ((size_t)b * 64 + tau) * 8 * 4096 + n;
#pragma unroll
    for (int r = 0; r < 4; ++r) {
      out[obase + (size_t)r * 4096]       = o0[r];
      out[obase + (size_t)(4 + r) * 4096] = o1[r];
    }
  }
}

// ---------- per-step state update (bf16 z out) + zero next parity gacc ----------
__global__ __launch_bounds__(256) void update_kernel(
    const float* __restrict__ zab, float* __restrict__ gacc,
    const float* __restrict__ bz, short* __restrict__ zout, int t) {
  const int par = t & 1;
  if (blockIdx.x == 0 && threadIdx.x < 16) gacc[(par ^ 1) * 16 + threadIdx.x] = 0.f;
  size_t idx = (size_t)blockIdx.x * 256 + threadIdx.x;   // 131072 threads
  size_t base = idx * 8;
  int row = (int)(base >> 12);
  int b = row >> 5, h = row & 31;
  float u  = gacc[par * 16 + b]     * (1.f / 131072.f);
  float fg = gacc[par * 16 + 8 + b] * (1.f / 131072.f);
  float bzv = bz[h];
  f32x4 za0 = *(const f32x4*)(zab + base),           za1 = *(const f32x4*)(zab + base + 4);
  f32x4 zb0 = *(const f32x4*)(zab + 1048576 + base), zb1 = *(const f32x4*)(zab + 1048576 + base + 4);
  bf16x8 ov;
#pragma unroll
  for (int i = 0; i < 4; ++i) {
    ov[i]     = f2b(tanh_f(u * za0[i] + fg * zb0[i] + bzv));
    ov[4 + i] = f2b(tanh_f(u * za1[i] + fg * zb1[i] + bzv));
  }
  *(bf16x8*)(zout + base) = ov;
}

// ---------- host ----------
extern "C" void kernel_launch(void* const* d_in, const int* in_sizes, int n_in,
                              void* d_out, int out_size, void* d_ws, size_t ws_size,
                              hipStream_t stream) {
  const float* x    = (const float*)d_in[0];
  const float* z0   = (const float*)d_in[1];
  const float* S    = (const float*)d_in[2];
  const float* Af   = (const float*)d_in[3];
  const float* Bw   = (const float*)d_in[4];
  const float* bz   = (const float*)d_in[5];
  const float* Ca   = (const float*)d_in[6];
  const float* Cb   = (const float*)d_in[7];
  const float* bc   = (const float*)d_in[8];
  const float* Da   = (const float*)d_in[9];
  const float* Db   = (const float*)d_in[10];
  const float* bd   = (const float*)d_in[11];
  const float* Wout = (const float*)d_in[12];
  const float* bo   = (const float*)d_in[13];
  const float* W1   = (const float*)d_in[14];
  const float* b1   = (const float*)d_in[15];
  const float* W2   = (const float*)d_in[16];
  const float* b2   = (const float*)d_in[17];
  float* out = (float*)d_out;

  // workspace layout (~151 MiB)
  char* w = (char*)d_ws;
  short* Scat = (short*)w; w += (size_t)8192 * 4096 * 2;   // bf16 [S ; S^2]          67.1 MB
  short* xsh  = (short*)w; w += (size_t)4096 * 8192 * 2;   // bf16 x shifts (tmp S^T) 67.1 MB
  short* zbuf = (short*)w; w += (size_t)2 * 1048576 * 2;   // bf16 z ping-pong         4.2 MB
  short* zsh  = (short*)w; w += (size_t)2097152 * 2;       // bf16 z shifts 256x8192   4.2 MB
  float* zab  = (float*)w; w += (size_t)2 * 1048576 * 4;   // fp32 za,zb               8.4 MB
  float* gacc = (float*)w; w += 256;                       // 2 parities x 16 floats
  size_t need = (size_t)(w - (char*)d_ws);
  if (ws_size < need) {
    fprintf(stderr, "kernel_launch: WS TOO SMALL need=%zu have=%zu -- NOT LAUNCHING\n",
            need, ws_size);
    return;
  }

  short* STt = xsh;  // temp: bf16 S^T (consumed by S^2 GEMM before xsh is written)

  conv_k<<<512, 256, 0, stream>>>(z0, zbuf, 131072);            // bf16 z_0
  conv_k<<<8192, 256, 0, stream>>>(S, Scat, 2097152);           // bf16 S
  transpose_k<<<dim3(128, 128), dim3(32, 8), 0, stream>>>(S, STt);
  gemm_pre<0><<<dim3(32, 32), 256, 0, stream>>>(Scat, STt, Scat + (size_t)4096 * 4096, 4096, 4096);
  gemm_pre<1><<<dim3(64, 32), 256, 0, stream>>>(x, Scat, xsh, 4096, 8192);
  hipMemsetAsync(gacc, 0, 128, stream);

  for (int t = 0; t <= 64; ++t) {
    short* zcur = zbuf + (size_t)(t & 1) * 1048576;
    short* znxt = zbuf + (size_t)((t + 1) & 1) * 1048576;
    gemm_zsh256<<<128, 256, 0, stream>>>(zcur, Scat, zsh);
    gateout_kernel<<<640, 256, 0, stream>>>(x, xsh, zcur, zsh,
                                            Ca, Cb, bc, Da, Db, bd, Af, Bw,
                                            Wout, bo, W1, b1, W2, b2,
                                            zab, gacc, out, t);
    if (t < 64)
      update_kernel<<<512, 256, 0, stream>>>(zab, gacc, bz, znxt, t);
  }
}